// Round 1
// baseline (1125.840 us; speedup 1.0000x reference)
//
#include <hip/hip_runtime.h>
#include <math.h>

namespace {

constexpr int kNpts = 1048576;
constexpr unsigned kTmask = 524287u;   // T = 2^19

struct ResArg { int r[16]; };

// Dense layer: weights in LDS (row-major [FI][FO]), bias from global (uniform
// -> scalar cache). Fully unrolled; float4 LDS broadcast reads.
template<int FI, int FO, bool RELU>
__device__ __forceinline__ void dense(const float* lw, const float* gb,
                                      const float* in, float* out) {
#pragma unroll
  for (int jg = 0; jg < FO / 16; ++jg) {
    float acc[16];
#pragma unroll
    for (int j = 0; j < 16; ++j) acc[j] = gb[jg * 16 + j];
#pragma unroll
    for (int i = 0; i < FI; ++i) {
      const float xi = in[i];
#pragma unroll
      for (int q = 0; q < 4; ++q) {
        const float4 w4 = *reinterpret_cast<const float4*>(lw + i * FO + jg * 16 + q * 4);
        acc[q * 4 + 0] = fmaf(xi, w4.x, acc[q * 4 + 0]);
        acc[q * 4 + 1] = fmaf(xi, w4.y, acc[q * 4 + 1]);
        acc[q * 4 + 2] = fmaf(xi, w4.z, acc[q * 4 + 2]);
        acc[q * 4 + 3] = fmaf(xi, w4.w, acc[q * 4 + 3]);
      }
    }
#pragma unroll
    for (int j = 0; j < 16; ++j) out[jg * 16 + j] = RELU ? fmaxf(acc[j], 0.f) : acc[j];
  }
}

__global__ __launch_bounds__(256) void nerf_fused(
    const float* __restrict__ xyz, const float* __restrict__ tables,
    const float* __restrict__ w1, const float* __restrict__ b1,
    const float* __restrict__ w2, const float* __restrict__ b2,
    const float* __restrict__ w3, const float* __restrict__ b3,
    const float* __restrict__ cw1, const float* __restrict__ cb1,
    const float* __restrict__ cw2, const float* __restrict__ cb2,
    const float* __restrict__ cw3, const float* __restrict__ cb3,
    const float* __restrict__ cw4, const float* __restrict__ cb4,
    float* __restrict__ out_color, float* __restrict__ out_sigma, ResArg res) {
  // LDS layout (floats): w1@0(2048) w2@2048(4096) w3@6144(1024)
  //                      cw1@7168(1024) cw2@8192(4096) cw3@12288(4096) = 16384 = 64KB
  __shared__ float smem[16384];
  const int tid = threadIdx.x;
  for (int t = tid; t < 2048; t += 256) smem[t] = w1[t];
  for (int t = tid; t < 4096; t += 256) smem[2048 + t] = w2[t];
  for (int t = tid; t < 1024; t += 256) smem[6144 + t] = w3[t];
  for (int t = tid; t < 1024; t += 256) smem[7168 + t] = cw1[t];
  for (int t = tid; t < 4096; t += 256) smem[8192 + t] = cw2[t];
  for (int t = tid; t < 4096; t += 256) smem[12288 + t] = cw3[t];
  __syncthreads();

  const int pt = blockIdx.x * 256 + tid;
  const float px = xyz[pt * 3 + 0];
  const float py = xyz[pt * 3 + 1];
  const float pz = xyz[pt * 3 + 2];

  float feat[32];
#pragma unroll
  for (int l = 0; l < 16; ++l) {
    const int R = res.r[l];
    const float Rf = (float)R;
    const float2* t2 = reinterpret_cast<const float2*>(tables + (size_t)l * 1048576u);
    const float sx = (px + 1.f) * 0.5f * (Rf - 1.f);
    const float sy = (py + 1.f) * 0.5f * (Rf - 1.f);
    const float sz = (pz + 1.f) * 0.5f * (Rf - 1.f);
    const float flx = floorf(sx), fly = floorf(sy), flz = floorf(sz);
    float fxw = sx - flx, fyw = sy - fly, fzw = sz - flz;
    int x0 = min(max((int)flx, 0), R - 1);
    int y0 = min(max((int)fly, 0), R - 1);
    int z0 = min(max((int)flz, 0), R - 1);
    int x1 = min(x0 + 1, R - 1), y1 = min(y0 + 1, R - 1), z1 = min(z0 + 1, R - 1);
    const unsigned hx0 = (unsigned)x0, hx1 = (unsigned)x1;
    const unsigned hy0 = (unsigned)y0 * 2654435761u, hy1 = (unsigned)y1 * 2654435761u;
    const unsigned hz0 = (unsigned)z0 * 805459861u, hz1 = (unsigned)z1 * 805459861u;
    const float wx1 = fxw, wx0 = 1.f - fxw;
    const float wy1 = fyw, wy0 = 1.f - fyw;
    const float wz1 = fzw, wz0 = 1.f - fzw;
    float a0 = 0.f, a1 = 0.f;
#define CORNER(HX, HY, HZ, WX, WY, WZ)                \
  do {                                                \
    const float2 e = t2[(HX ^ HY ^ HZ) & kTmask];     \
    const float w = (WX) * (WY) * (WZ);               \
    a0 = fmaf(w, e.x, a0);                            \
    a1 = fmaf(w, e.y, a1);                            \
  } while (0)
    CORNER(hx0, hy0, hz0, wx0, wy0, wz0);
    CORNER(hx0, hy0, hz1, wx0, wy0, wz1);
    CORNER(hx0, hy1, hz0, wx0, wy1, wz0);
    CORNER(hx0, hy1, hz1, wx0, wy1, wz1);
    CORNER(hx1, hy0, hz0, wx1, wy0, wz0);
    CORNER(hx1, hy0, hz1, wx1, wy0, wz1);
    CORNER(hx1, hy1, hz0, wx1, wy1, wz0);
    CORNER(hx1, hy1, hz1, wx1, wy1, wz1);
#undef CORNER
    feat[2 * l + 0] = a0;
    feat[2 * l + 1] = a1;
  }

  // density MLP: 32 -> 64 -> 64 -> 16
  float h1[64], h2[64], f[16];
  dense<32, 64, true>(smem + 0, b1, feat, h1);
  dense<64, 64, true>(smem + 2048, b2, h1, h2);
  dense<64, 16, false>(smem + 6144, b3, h2, f);
  const float sigma = expf(f[0]);

  // color MLP: 16 -> 64 -> 64 -> 64 -> 3
  float y1[64], y2[64], y3[64];
  dense<16, 64, true>(smem + 7168, cb1, f, y1);
  dense<64, 64, true>(smem + 8192, cb2, y1, y2);
  dense<64, 64, true>(smem + 12288, cb3, y2, y3);

  float c0 = cb4[0], c1 = cb4[1], c2 = cb4[2];
#pragma unroll
  for (int i = 0; i < 64; ++i) {
    const float yi = y3[i];
    c0 = fmaf(yi, cw4[i * 3 + 0], c0);
    c1 = fmaf(yi, cw4[i * 3 + 1], c1);
    c2 = fmaf(yi, cw4[i * 3 + 2], c2);
  }
  out_color[pt * 3 + 0] = 1.f / (1.f + expf(-c0));
  out_color[pt * 3 + 1] = 1.f / (1.f + expf(-c1));
  out_color[pt * 3 + 2] = 1.f / (1.f + expf(-c2));
  out_sigma[pt] = sigma;
}

}  // namespace

extern "C" void kernel_launch(void* const* d_in, const int* in_sizes, int n_in,
                              void* d_out, int out_size, void* d_ws, size_t ws_size,
                              hipStream_t stream) {
  const float* xyz = (const float*)d_in[0];
  const float* tables = (const float*)d_in[1];
  const float* w1 = (const float*)d_in[2];
  const float* b1 = (const float*)d_in[3];
  const float* w2 = (const float*)d_in[4];
  const float* b2 = (const float*)d_in[5];
  const float* w3 = (const float*)d_in[6];
  const float* b3 = (const float*)d_in[7];
  const float* cw1 = (const float*)d_in[8];
  const float* cb1 = (const float*)d_in[9];
  const float* cw2 = (const float*)d_in[10];
  const float* cb2 = (const float*)d_in[11];
  const float* cw3 = (const float*)d_in[12];
  const float* cb3 = (const float*)d_in[13];
  const float* cw4 = (const float*)d_in[14];
  const float* cb4 = (const float*)d_in[15];
  float* out = (float*)d_out;

  // Replicate numpy: RES = floor(16 * exp(arange(16) * (log(2048)-log(16)) / 15))
  ResArg ra;
  const double diff = log(2048.0) - log(16.0);
  for (int l = 0; l < 16; ++l) ra.r[l] = (int)floor(16.0 * exp((double)l * diff / 15.0));

  dim3 grid(kNpts / 256), block(256);
  hipLaunchKernelGGL(nerf_fused, grid, block, 0, stream, xyz, tables, w1, b1, w2, b2,
                     w3, b3, cw1, cb1, cw2, cb2, cw3, cb3, cw4, cb4, out,
                     out + (size_t)3 * kNpts, ra);
}

// Round 4
// 966.608 us; speedup vs baseline: 1.1647x; 1.1647x over previous
//
#include <hip/hip_runtime.h>
#include <math.h>

typedef long long i64;
typedef __attribute__((ext_vector_type(4))) float float4v;

namespace {

constexpr int kNpts = 1048576;
constexpr unsigned kTmask = 524287u;   // T = 2^19
constexpr float kS = 4096.0f;          // activation scale into fp8
constexpr float kInvS = 1.0f / 4096.0f;
constexpr float kClamp = 448.0f;       // e4m3fn max normal
constexpr int NB = 4;                  // point-batches per block (amortize weight prep)
constexpr int BLK = 256;

// LDS layout (bytes)
constexpr int W_OFF = 0;       // 36 frags * 512B = 18432 (fp8 A-fragments of W^T)
constexpr int B_OFF = 18432;   // 400 floats = 1600 (biases)
constexpr int F_OFF = 20032;   // 256 pts * 32 fp8 = 8192 (feats, B-frag order)
constexpr int S_OFF = 28224;   // 4 waves * 1152B (activation relayout scratch)
constexpr int LDS_BYTES = 32832;

struct ResArg { int r[16]; };

__device__ __forceinline__ unsigned char f2fp8(float v) {
  return (unsigned char)(__builtin_amdgcn_cvt_pk_fp8_f32(v, 0.f, 0, false) & 0xff);
}

// Stage one weight matrix (raw [K][OUT] fp32) into LDS as fp8 A-fragments of W^T.
// Frag f = FBASE + t*(Kp/32) + h holds A[m][k]: m = 16t + (l&15), k = 32h + 8*(l>>4) + j.
template<int K, int OUT, int Kp, int OUTp, int FBASE>
__device__ __forceinline__ void prep_layer(char* wl, const float* __restrict__ w, int tid) {
  constexpr int N = Kp * OUTp;
  for (int e = tid; e < N; e += BLK) {
    const int k = e / OUTp, o = e % OUTp;
    const float v = (k < K && o < OUT) ? w[k * OUT + o] : 0.f;
    const int f = FBASE + (o >> 4) * (Kp >> 5) + (k >> 5);
    const int l = (o & 15) | (((k >> 3) & 3) << 4);
    wl[f * 512 + l * 8 + (k & 7)] = (char)f2fp8(v);
  }
}

__device__ __forceinline__ i64 ldsA(const char* wl, int f, int lane) {
  return *(const i64*)(wl + f * 512 + lane * 8);
}
__device__ __forceinline__ i64 rB(const char* scr, int p, int g, int h) {
  return *(const i64*)(scr + p * 72 + h * 32 + g * 8);
}
__device__ __forceinline__ float4v bias4(const float* bl, int boff, int t, int g) {
  return *(const float4v*)(bl + boff + t * 16 + g * 4) * kS;
}
// Store a 4-tile (64-wide) activation layer to scratch as fp8 (ReLU'd, clamped).
__device__ __forceinline__ void store_act4(char* scr, const float4v a[4], int p, int g) {
  #pragma unroll
  for (int t = 0; t < 4; ++t) {
    const float x0 = fminf(fmaxf(a[t].x, 0.f), kClamp);
    const float x1 = fminf(fmaxf(a[t].y, 0.f), kClamp);
    const float x2 = fminf(fmaxf(a[t].z, 0.f), kClamp);
    const float x3 = fminf(fmaxf(a[t].w, 0.f), kClamp);
    int d = __builtin_amdgcn_cvt_pk_fp8_f32(x0, x1, 0, false);
    d = __builtin_amdgcn_cvt_pk_fp8_f32(x2, x3, d, true);
    *(int*)(scr + p * 72 + t * 16 + g * 4) = d;
  }
}

#define MFMA8(A, B, C) __builtin_amdgcn_mfma_f32_16x16x32_fp8_fp8((A), (B), (C), 0, 0, 0)
#define LDS_FENCE() __threadfence_block()

__global__ __launch_bounds__(BLK, 4) void nerf_fused(
    const float* __restrict__ xyz, const float* __restrict__ tables,
    const float* __restrict__ w1, const float* __restrict__ b1,
    const float* __restrict__ w2, const float* __restrict__ b2,
    const float* __restrict__ w3, const float* __restrict__ b3,
    const float* __restrict__ cw1, const float* __restrict__ cb1,
    const float* __restrict__ cw2, const float* __restrict__ cb2,
    const float* __restrict__ cw3, const float* __restrict__ cb3,
    const float* __restrict__ cw4, const float* __restrict__ cb4,
    float* __restrict__ out_color, float* __restrict__ out_sigma, ResArg res) {
  __shared__ __align__(16) char smem[LDS_BYTES];
  const int tid = threadIdx.x;
  char* wl = smem + W_OFF;
  float* bl = (float*)(smem + B_OFF);

  // ---- one-time per-block weight/bias staging ----
  prep_layer<32, 64, 32, 64, 0>(wl, w1, tid);
  prep_layer<64, 64, 64, 64, 4>(wl, w2, tid);
  prep_layer<64, 16, 64, 16, 12>(wl, w3, tid);
  prep_layer<16, 64, 32, 64, 14>(wl, cw1, tid);
  prep_layer<64, 64, 64, 64, 18>(wl, cw2, tid);
  prep_layer<64, 64, 64, 64, 26>(wl, cw3, tid);
  prep_layer<64, 3, 64, 16, 34>(wl, cw4, tid);
  if (tid < 64) {
    bl[0 + tid] = b1[tid];  bl[64 + tid] = b2[tid];
    bl[192 + tid] = cb1[tid]; bl[256 + tid] = cb2[tid]; bl[320 + tid] = cb3[tid];
  }
  if (tid < 16) { bl[128 + tid] = b3[tid]; bl[384 + tid] = (tid < 3) ? cb4[tid] : 0.f; }
  __syncthreads();

  const int lane = tid & 63, wave = tid >> 6;
  const int p = lane & 15, g = lane >> 4;
  char* feat_all = smem + F_OFF;
  const char* fw = smem + F_OFF + wave * 2048;
  char* scr = smem + S_OFF + wave * 1152;

  for (int b = 0; b < NB; ++b) {
    const int base = (blockIdx.x * NB + b) * BLK;
    LDS_FENCE();  // WAR: previous iteration's reads complete before overwrite

    // ---- phase 1: hash-grid gather (thread-per-point), pack fp8 feats to LDS ----
    {
      const int pt = base + tid;
      const float px = xyz[pt * 3 + 0];
      const float py = xyz[pt * 3 + 1];
      const float pz = xyz[pt * 3 + 2];
      unsigned dws[8] = {0, 0, 0, 0, 0, 0, 0, 0};
#pragma unroll
      for (int l = 0; l < 16; ++l) {
        const int R = res.r[l];
        const float Rf = (float)R;
        const float2* t2 = reinterpret_cast<const float2*>(tables + (size_t)l * 1048576u);
        const float sx = (px + 1.f) * 0.5f * (Rf - 1.f);
        const float sy = (py + 1.f) * 0.5f * (Rf - 1.f);
        const float sz = (pz + 1.f) * 0.5f * (Rf - 1.f);
        const float flx = floorf(sx), fly = floorf(sy), flz = floorf(sz);
        const float fxw = sx - flx, fyw = sy - fly, fzw = sz - flz;
        const int x0 = min(max((int)flx, 0), R - 1);
        const int y0 = min(max((int)fly, 0), R - 1);
        const int z0 = min(max((int)flz, 0), R - 1);
        const int x1 = min(x0 + 1, R - 1), y1 = min(y0 + 1, R - 1), z1 = min(z0 + 1, R - 1);
        const unsigned hx0 = (unsigned)x0, hx1 = (unsigned)x1;
        const unsigned hy0 = (unsigned)y0 * 2654435761u, hy1 = (unsigned)y1 * 2654435761u;
        const unsigned hz0 = (unsigned)z0 * 805459861u, hz1 = (unsigned)z1 * 805459861u;
        const float wx1 = fxw, wx0 = 1.f - fxw;
        const float wy1 = fyw, wy0 = 1.f - fyw;
        const float wz1 = fzw, wz0 = 1.f - fzw;
        float a0 = 0.f, a1 = 0.f;
#define CORNER(HX, HY, HZ, WX, WY, WZ)              \
  do {                                              \
    const float2 e = t2[(HX ^ HY ^ HZ) & kTmask];   \
    const float w = (WX) * (WY) * (WZ);             \
    a0 = fmaf(w, e.x, a0);                          \
    a1 = fmaf(w, e.y, a1);                          \
  } while (0)
        CORNER(hx0, hy0, hz0, wx0, wy0, wz0);
        CORNER(hx0, hy0, hz1, wx0, wy0, wz1);
        CORNER(hx0, hy1, hz0, wx0, wy1, wz0);
        CORNER(hx0, hy1, hz1, wx0, wy1, wz1);
        CORNER(hx1, hy0, hz0, wx1, wy0, wz0);
        CORNER(hx1, hy0, hz1, wx1, wy0, wz1);
        CORNER(hx1, hy1, hz0, wx1, wy1, wz0);
        CORNER(hx1, hy1, hz1, wx1, wy1, wz1);
#undef CORNER
        const unsigned v =
            (unsigned)__builtin_amdgcn_cvt_pk_fp8_f32(a0 * kS, a1 * kS, 0, false) & 0xffffu;
        dws[l >> 1] |= v << (16 * (l & 1));
      }
      // feats B-frag layout: tile P=tid>>4, chunk g at P*512 + g*128 + (tid&15)*8
      char* fb = feat_all + (tid >> 4) * 512 + (tid & 15) * 8;
#pragma unroll
      for (int gg = 0; gg < 4; ++gg)
        *(int2*)(fb + gg * 128) = make_int2((int)dws[2 * gg], (int)dws[2 * gg + 1]);
    }
    LDS_FENCE();  // RAW: feat writes visible before fragment reads (same wave, cross-lane)

    // ---- phase 2: MFMA MLP, wave processes its 64 points as 4 N-tiles of 16 ----
    const int ptb = base + wave * 64;
    for (int n = 0; n < 4; ++n) {
      const i64 Bf = *(const i64*)(fw + n * 512 + lane * 8);
      float4v a[4];
      // L1: 32 -> 64 (frags 0..3, K=32)
#pragma unroll
      for (int t = 0; t < 4; ++t) a[t] = MFMA8(ldsA(wl, 0 + t, lane), Bf, bias4(bl, 0, t, g));
      store_act4(scr, a, p, g);
      LDS_FENCE();
      i64 B0 = rB(scr, p, g, 0), B1 = rB(scr, p, g, 1);
      // L2: 64 -> 64 (frags 4..11)
#pragma unroll
      for (int t = 0; t < 4; ++t) {
        float4v c = bias4(bl, 64, t, g);
        c = MFMA8(ldsA(wl, 4 + 2 * t, lane), B0, c);
        a[t] = MFMA8(ldsA(wl, 5 + 2 * t, lane), B1, c);
      }
      store_act4(scr, a, p, g);
      LDS_FENCE();
      B0 = rB(scr, p, g, 0); B1 = rB(scr, p, g, 1);
      // L3: 64 -> 16 (frags 12,13), no relu
      float4v f4 = bias4(bl, 128, 0, g);
      f4 = MFMA8(ldsA(wl, 12, lane), B0, f4);
      f4 = MFMA8(ldsA(wl, 13, lane), B1, f4);
      if (g == 0) out_sigma[ptb + n * 16 + p] = expf(f4.x * kInvS);
      {
        const float z0 = fminf(fmaxf(f4.x, -kClamp), kClamp);
        const float z1 = fminf(fmaxf(f4.y, -kClamp), kClamp);
        const float z2 = fminf(fmaxf(f4.z, -kClamp), kClamp);
        const float z3 = fminf(fmaxf(f4.w, -kClamp), kClamp);
        int d = __builtin_amdgcn_cvt_pk_fp8_f32(z0, z1, 0, false);
        d = __builtin_amdgcn_cvt_pk_fp8_f32(z2, z3, d, true);
        *(int*)(scr + p * 72 + g * 4) = d;
      }
      LDS_FENCE();
      const i64 Bc = rB(scr, p, g, 0);  // K=16 padded to 32 (pad weights are 0)
      // C1: 16 -> 64 (frags 14..17)
#pragma unroll
      for (int t = 0; t < 4; ++t) a[t] = MFMA8(ldsA(wl, 14 + t, lane), Bc, bias4(bl, 192, t, g));
      store_act4(scr, a, p, g);
      LDS_FENCE();
      B0 = rB(scr, p, g, 0); B1 = rB(scr, p, g, 1);
      // C2: 64 -> 64 (frags 18..25)
#pragma unroll
      for (int t = 0; t < 4; ++t) {
        float4v c = bias4(bl, 256, t, g);
        c = MFMA8(ldsA(wl, 18 + 2 * t, lane), B0, c);
        a[t] = MFMA8(ldsA(wl, 19 + 2 * t, lane), B1, c);
      }
      store_act4(scr, a, p, g);
      LDS_FENCE();
      B0 = rB(scr, p, g, 0); B1 = rB(scr, p, g, 1);
      // C3: 64 -> 64 (frags 26..33)
#pragma unroll
      for (int t = 0; t < 4; ++t) {
        float4v c = bias4(bl, 320, t, g);
        c = MFMA8(ldsA(wl, 26 + 2 * t, lane), B0, c);
        a[t] = MFMA8(ldsA(wl, 27 + 2 * t, lane), B1, c);
      }
      store_act4(scr, a, p, g);
      LDS_FENCE();
      B0 = rB(scr, p, g, 0); B1 = rB(scr, p, g, 1);
      // C4: 64 -> 3 (padded 16) (frags 34,35)
      float4v c4 = bias4(bl, 384, 0, g);
      c4 = MFMA8(ldsA(wl, 34, lane), B0, c4);
      c4 = MFMA8(ldsA(wl, 35, lane), B1, c4);
      if (g == 0) {
        const int pt = ptb + n * 16 + p;
        out_color[pt * 3 + 0] = 1.f / (1.f + expf(-c4.x * kInvS));
        out_color[pt * 3 + 1] = 1.f / (1.f + expf(-c4.y * kInvS));
        out_color[pt * 3 + 2] = 1.f / (1.f + expf(-c4.z * kInvS));
      }
      LDS_FENCE();  // WAR: scr reads done before next n overwrites
    }
  }
}

}  // namespace

extern "C" void kernel_launch(void* const* d_in, const int* in_sizes, int n_in,
                              void* d_out, int out_size, void* d_ws, size_t ws_size,
                              hipStream_t stream) {
  const float* xyz = (const float*)d_in[0];
  const float* tables = (const float*)d_in[1];
  const float* w1 = (const float*)d_in[2];
  const float* b1 = (const float*)d_in[3];
  const float* w2 = (const float*)d_in[4];
  const float* b2 = (const float*)d_in[5];
  const float* w3 = (const float*)d_in[6];
  const float* b3 = (const float*)d_in[7];
  const float* cw1 = (const float*)d_in[8];
  const float* cb1 = (const float*)d_in[9];
  const float* cw2 = (const float*)d_in[10];
  const float* cb2 = (const float*)d_in[11];
  const float* cw3 = (const float*)d_in[12];
  const float* cb3 = (const float*)d_in[13];
  const float* cw4 = (const float*)d_in[14];
  const float* cb4 = (const float*)d_in[15];
  float* out = (float*)d_out;

  ResArg ra;
  const double diff = log(2048.0) - log(16.0);
  for (int l = 0; l < 16; ++l) ra.r[l] = (int)floor(16.0 * exp((double)l * diff / 15.0));

  dim3 grid(kNpts / (BLK * NB)), block(BLK);
  hipLaunchKernelGGL(nerf_fused, grid, block, 0, stream, xyz, tables, w1, b1, w2, b2,
                     w3, b3, cw1, cb1, cw2, cb2, cw3, cb3, cw4, cb4, out,
                     out + (size_t)3 * kNpts, ra);
}

// Round 5
// 776.836 us; speedup vs baseline: 1.4493x; 1.2443x over previous
//
#include <hip/hip_runtime.h>
#include <math.h>

typedef long long i64;
typedef __attribute__((ext_vector_type(4))) float float4v;

namespace {

constexpr int kNpts = 1048576;
constexpr unsigned kTmask = 524287u;   // T = 2^19
constexpr float kS = 4096.0f;          // activation scale into fp8
constexpr float kInvS = 1.0f / 4096.0f;
constexpr float kClamp = 448.0f;       // e4m3fn max normal
constexpr int NB = 4;                  // point-batches per block in MLP kernel
constexpr int BLK = 256;

// MLP kernel LDS layout (bytes)
constexpr int W_OFF = 0;       // 36 frags * 512B = 18432 (fp8 A-fragments of W^T)
constexpr int B_OFF = 18432;   // 400 floats = 1600 (biases)
constexpr int S_OFF = 20032;   // 4 waves * 1152B (activation relayout scratch)
constexpr int LDS_BYTES = 24640;

struct ResArg { int r[16]; };

__device__ __forceinline__ unsigned char f2fp8(float v) {
  return (unsigned char)(__builtin_amdgcn_cvt_pk_fp8_f32(v, 0.f, 0, false) & 0xff);
}

// Stage one weight matrix (raw [K][OUT] fp32) into LDS as fp8 A-fragments of W^T.
// Frag f = FBASE + t*(Kp/32) + h holds A[m][k]: m = 16t + (l&15), k = 32h + 8*(l>>4) + j.
template<int K, int OUT, int Kp, int OUTp, int FBASE>
__device__ __forceinline__ void prep_layer(char* wl, const float* __restrict__ w, int tid) {
  constexpr int N = Kp * OUTp;
  for (int e = tid; e < N; e += BLK) {
    const int k = e / OUTp, o = e % OUTp;
    const float v = (k < K && o < OUT) ? w[k * OUT + o] : 0.f;
    const int f = FBASE + (o >> 4) * (Kp >> 5) + (k >> 5);
    const int l = (o & 15) | (((k >> 3) & 3) << 4);
    wl[f * 512 + l * 8 + (k & 7)] = (char)f2fp8(v);
  }
}

__device__ __forceinline__ i64 ldsA(const char* wl, int f, int lane) {
  return *(const i64*)(wl + f * 512 + lane * 8);
}
__device__ __forceinline__ i64 rB(const char* scr, int p, int g, int h) {
  return *(const i64*)(scr + p * 72 + h * 32 + g * 8);
}
__device__ __forceinline__ float4v bias4(const float* bl, int boff, int t, int g) {
  return *(const float4v*)(bl + boff + t * 16 + g * 4) * kS;
}
__device__ __forceinline__ void store_act4(char* scr, const float4v a[4], int p, int g) {
  #pragma unroll
  for (int t = 0; t < 4; ++t) {
    const float x0 = fminf(fmaxf(a[t].x, 0.f), kClamp);
    const float x1 = fminf(fmaxf(a[t].y, 0.f), kClamp);
    const float x2 = fminf(fmaxf(a[t].z, 0.f), kClamp);
    const float x3 = fminf(fmaxf(a[t].w, 0.f), kClamp);
    int d = __builtin_amdgcn_cvt_pk_fp8_f32(x0, x1, 0, false);
    d = __builtin_amdgcn_cvt_pk_fp8_f32(x2, x3, d, true);
    *(int*)(scr + p * 72 + t * 16 + g * 4) = d;
  }
}

#define MFMA8(A, B, C) __builtin_amdgcn_mfma_f32_16x16x32_fp8_fp8((A), (B), (C), 0, 0, 0)
#define LDS_FENCE() __threadfence_block()

// ---------------- Kernel A: hash-grid gather, one thread = (point, level) ---
// Grid: bid = chunk*16 + level  ->  XCD = bid%8 = level%8 (round-robin):
// each XCD's L2 only sees 2 levels' tables (4-8 MB) instead of all 16 (53 MB).
__global__ __launch_bounds__(BLK, 8) void hash_gather(
    const float* __restrict__ xyz, const float* __restrict__ tables,
    unsigned char* __restrict__ feats, ResArg res) {
  const int bid = blockIdx.x;
  const int level = bid & 15;
  const int pt = (bid >> 4) * BLK + threadIdx.x;

  const float px = xyz[pt * 3 + 0];
  const float py = xyz[pt * 3 + 1];
  const float pz = xyz[pt * 3 + 2];

  const int R = res.r[level];
  const float Rf = (float)R;
  const float2* t2 = reinterpret_cast<const float2*>(tables + (size_t)level * 1048576u);
  const float sx = (px + 1.f) * 0.5f * (Rf - 1.f);
  const float sy = (py + 1.f) * 0.5f * (Rf - 1.f);
  const float sz = (pz + 1.f) * 0.5f * (Rf - 1.f);
  const float flx = floorf(sx), fly = floorf(sy), flz = floorf(sz);
  const float fxw = sx - flx, fyw = sy - fly, fzw = sz - flz;
  const int x0 = min(max((int)flx, 0), R - 1);
  const int y0 = min(max((int)fly, 0), R - 1);
  const int z0 = min(max((int)flz, 0), R - 1);
  const int x1 = min(x0 + 1, R - 1), y1 = min(y0 + 1, R - 1), z1 = min(z0 + 1, R - 1);
  const unsigned hx0 = (unsigned)x0, hx1 = (unsigned)x1;
  const unsigned hy0 = (unsigned)y0 * 2654435761u, hy1 = (unsigned)y1 * 2654435761u;
  const unsigned hz0 = (unsigned)z0 * 805459861u, hz1 = (unsigned)z1 * 805459861u;
  // issue all 8 loads up front (independent -> 8 outstanding per lane)
  const float2 e000 = t2[(hx0 ^ hy0 ^ hz0) & kTmask];
  const float2 e001 = t2[(hx0 ^ hy0 ^ hz1) & kTmask];
  const float2 e010 = t2[(hx0 ^ hy1 ^ hz0) & kTmask];
  const float2 e011 = t2[(hx0 ^ hy1 ^ hz1) & kTmask];
  const float2 e100 = t2[(hx1 ^ hy0 ^ hz0) & kTmask];
  const float2 e101 = t2[(hx1 ^ hy0 ^ hz1) & kTmask];
  const float2 e110 = t2[(hx1 ^ hy1 ^ hz0) & kTmask];
  const float2 e111 = t2[(hx1 ^ hy1 ^ hz1) & kTmask];
  const float wx1 = fxw, wx0 = 1.f - fxw;
  const float wy1 = fyw, wy0 = 1.f - fyw;
  const float wz1 = fzw, wz0 = 1.f - fzw;
  float a0 = 0.f, a1 = 0.f;
  float w;
  w = wx0 * wy0 * wz0; a0 = fmaf(w, e000.x, a0); a1 = fmaf(w, e000.y, a1);
  w = wx0 * wy0 * wz1; a0 = fmaf(w, e001.x, a0); a1 = fmaf(w, e001.y, a1);
  w = wx0 * wy1 * wz0; a0 = fmaf(w, e010.x, a0); a1 = fmaf(w, e010.y, a1);
  w = wx0 * wy1 * wz1; a0 = fmaf(w, e011.x, a0); a1 = fmaf(w, e011.y, a1);
  w = wx1 * wy0 * wz0; a0 = fmaf(w, e100.x, a0); a1 = fmaf(w, e100.y, a1);
  w = wx1 * wy0 * wz1; a0 = fmaf(w, e101.x, a0); a1 = fmaf(w, e101.y, a1);
  w = wx1 * wy1 * wz0; a0 = fmaf(w, e110.x, a0); a1 = fmaf(w, e110.y, a1);
  w = wx1 * wy1 * wz1; a0 = fmaf(w, e111.x, a0); a1 = fmaf(w, e111.y, a1);

  const unsigned v =
      (unsigned)__builtin_amdgcn_cvt_pk_fp8_f32(a0 * kS, a1 * kS, 0, false) & 0xffffu;
  // B-fragment byte order: tile=pt>>4, lane p=pt&15, bytes k=2l,2l+1 at
  // tile*512 + (k>>3)*128 + p*8 + (k&7); (2l)>>3 == l>>2, (2l)&7 == (2l)&6.
  *(unsigned short*)(feats + (size_t)(pt >> 4) * 512 + (level >> 2) * 128 +
                     (pt & 15) * 8 + ((2 * level) & 6)) = (unsigned short)v;
}

// ---------------- Kernel B: MFMA MLP over precomputed feats -----------------
__global__ __launch_bounds__(BLK, 4) void nerf_mlp(
    const unsigned char* __restrict__ feats,
    const float* __restrict__ w1, const float* __restrict__ b1,
    const float* __restrict__ w2, const float* __restrict__ b2,
    const float* __restrict__ w3, const float* __restrict__ b3,
    const float* __restrict__ cw1, const float* __restrict__ cb1,
    const float* __restrict__ cw2, const float* __restrict__ cb2,
    const float* __restrict__ cw3, const float* __restrict__ cb3,
    const float* __restrict__ cw4, const float* __restrict__ cb4,
    float* __restrict__ out_color, float* __restrict__ out_sigma) {
  __shared__ __align__(16) char smem[LDS_BYTES];
  const int tid = threadIdx.x;
  char* wl = smem + W_OFF;
  float* bl = (float*)(smem + B_OFF);

  prep_layer<32, 64, 32, 64, 0>(wl, w1, tid);
  prep_layer<64, 64, 64, 64, 4>(wl, w2, tid);
  prep_layer<64, 16, 64, 16, 12>(wl, w3, tid);
  prep_layer<16, 64, 32, 64, 14>(wl, cw1, tid);
  prep_layer<64, 64, 64, 64, 18>(wl, cw2, tid);
  prep_layer<64, 64, 64, 64, 26>(wl, cw3, tid);
  prep_layer<64, 3, 64, 16, 34>(wl, cw4, tid);
  if (tid < 64) {
    bl[0 + tid] = b1[tid];  bl[64 + tid] = b2[tid];
    bl[192 + tid] = cb1[tid]; bl[256 + tid] = cb2[tid]; bl[320 + tid] = cb3[tid];
  }
  if (tid < 16) { bl[128 + tid] = b3[tid]; bl[384 + tid] = (tid < 3) ? cb4[tid] : 0.f; }
  __syncthreads();

  const int lane = tid & 63, wave = tid >> 6;
  const int p = lane & 15, g = lane >> 4;
  char* scr = smem + S_OFF + wave * 1152;

  for (int b = 0; b < NB; ++b) {
    const int base = (blockIdx.x * NB + b) * BLK;
    const int ptb = base + wave * 64;
    for (int n = 0; n < 4; ++n) {
      const int tile = (ptb >> 4) + n;
      const i64 Bf = *(const i64*)(feats + (size_t)tile * 512 + g * 128 + p * 8);
      float4v a[4];
      // L1: 32 -> 64 (frags 0..3, K=32)
#pragma unroll
      for (int t = 0; t < 4; ++t) a[t] = MFMA8(ldsA(wl, 0 + t, lane), Bf, bias4(bl, 0, t, g));
      store_act4(scr, a, p, g);
      LDS_FENCE();
      i64 B0 = rB(scr, p, g, 0), B1 = rB(scr, p, g, 1);
      // L2: 64 -> 64 (frags 4..11)
#pragma unroll
      for (int t = 0; t < 4; ++t) {
        float4v c = bias4(bl, 64, t, g);
        c = MFMA8(ldsA(wl, 4 + 2 * t, lane), B0, c);
        a[t] = MFMA8(ldsA(wl, 5 + 2 * t, lane), B1, c);
      }
      store_act4(scr, a, p, g);
      LDS_FENCE();
      B0 = rB(scr, p, g, 0); B1 = rB(scr, p, g, 1);
      // L3: 64 -> 16 (frags 12,13), no relu
      float4v f4 = bias4(bl, 128, 0, g);
      f4 = MFMA8(ldsA(wl, 12, lane), B0, f4);
      f4 = MFMA8(ldsA(wl, 13, lane), B1, f4);
      if (g == 0) out_sigma[ptb + n * 16 + p] = expf(f4.x * kInvS);
      {
        const float z0 = fminf(fmaxf(f4.x, -kClamp), kClamp);
        const float z1 = fminf(fmaxf(f4.y, -kClamp), kClamp);
        const float z2 = fminf(fmaxf(f4.z, -kClamp), kClamp);
        const float z3 = fminf(fmaxf(f4.w, -kClamp), kClamp);
        int d = __builtin_amdgcn_cvt_pk_fp8_f32(z0, z1, 0, false);
        d = __builtin_amdgcn_cvt_pk_fp8_f32(z2, z3, d, true);
        *(int*)(scr + p * 72 + g * 4) = d;
      }
      LDS_FENCE();
      const i64 Bc = rB(scr, p, g, 0);  // K=16 padded to 32 (pad weights are 0)
      // C1: 16 -> 64 (frags 14..17)
#pragma unroll
      for (int t = 0; t < 4; ++t) a[t] = MFMA8(ldsA(wl, 14 + t, lane), Bc, bias4(bl, 192, t, g));
      store_act4(scr, a, p, g);
      LDS_FENCE();
      B0 = rB(scr, p, g, 0); B1 = rB(scr, p, g, 1);
      // C2: 64 -> 64 (frags 18..25)
#pragma unroll
      for (int t = 0; t < 4; ++t) {
        float4v c = bias4(bl, 256, t, g);
        c = MFMA8(ldsA(wl, 18 + 2 * t, lane), B0, c);
        a[t] = MFMA8(ldsA(wl, 19 + 2 * t, lane), B1, c);
      }
      store_act4(scr, a, p, g);
      LDS_FENCE();
      B0 = rB(scr, p, g, 0); B1 = rB(scr, p, g, 1);
      // C3: 64 -> 64 (frags 26..33)
#pragma unroll
      for (int t = 0; t < 4; ++t) {
        float4v c = bias4(bl, 320, t, g);
        c = MFMA8(ldsA(wl, 26 + 2 * t, lane), B0, c);
        a[t] = MFMA8(ldsA(wl, 27 + 2 * t, lane), B1, c);
      }
      store_act4(scr, a, p, g);
      LDS_FENCE();
      B0 = rB(scr, p, g, 0); B1 = rB(scr, p, g, 1);
      // C4: 64 -> 3 (padded 16) (frags 34,35)
      float4v c4 = bias4(bl, 384, 0, g);
      c4 = MFMA8(ldsA(wl, 34, lane), B0, c4);
      c4 = MFMA8(ldsA(wl, 35, lane), B1, c4);
      if (g == 0) {
        const int pt = ptb + n * 16 + p;
        out_color[pt * 3 + 0] = 1.f / (1.f + expf(-c4.x * kInvS));
        out_color[pt * 3 + 1] = 1.f / (1.f + expf(-c4.y * kInvS));
        out_color[pt * 3 + 2] = 1.f / (1.f + expf(-c4.z * kInvS));
      }
      LDS_FENCE();  // WAR: scr reads done before next n overwrites
    }
  }
}

}  // namespace

extern "C" void kernel_launch(void* const* d_in, const int* in_sizes, int n_in,
                              void* d_out, int out_size, void* d_ws, size_t ws_size,
                              hipStream_t stream) {
  const float* xyz = (const float*)d_in[0];
  const float* tables = (const float*)d_in[1];
  const float* w1 = (const float*)d_in[2];
  const float* b1 = (const float*)d_in[3];
  const float* w2 = (const float*)d_in[4];
  const float* b2 = (const float*)d_in[5];
  const float* w3 = (const float*)d_in[6];
  const float* b3 = (const float*)d_in[7];
  const float* cw1 = (const float*)d_in[8];
  const float* cb1 = (const float*)d_in[9];
  const float* cw2 = (const float*)d_in[10];
  const float* cb2 = (const float*)d_in[11];
  const float* cw3 = (const float*)d_in[12];
  const float* cb3 = (const float*)d_in[13];
  const float* cw4 = (const float*)d_in[14];
  const float* cb4 = (const float*)d_in[15];
  float* out = (float*)d_out;
  unsigned char* feats = (unsigned char*)d_ws;  // 32 MB: 1M pts * 32 fp8 bytes

  ResArg ra;
  const double diff = log(2048.0) - log(16.0);
  for (int l = 0; l < 16; ++l) ra.r[l] = (int)floor(16.0 * exp((double)l * diff / 15.0));

  hipLaunchKernelGGL(hash_gather, dim3((kNpts / BLK) * 16), dim3(BLK), 0, stream,
                     xyz, tables, feats, ra);
  hipLaunchKernelGGL(nerf_mlp, dim3(kNpts / (BLK * NB)), dim3(BLK), 0, stream,
                     feats, w1, b1, w2, b2, w3, b3, cw1, cb1, cw2, cb2, cw3, cb3,
                     cw4, cb4, out, out + (size_t)3 * kNpts);
}

// Round 6
// 619.757 us; speedup vs baseline: 1.8166x; 1.2535x over previous
//
#include <hip/hip_runtime.h>
#include <math.h>

typedef long long i64;
typedef __attribute__((ext_vector_type(4))) float float4v;

namespace {

constexpr int kNpts = 1048576;
constexpr unsigned kTmask = 524287u;   // T = 2^19
constexpr float kS = 4096.0f;          // activation scale into fp8
constexpr float kInvS = 1.0f / 4096.0f;
constexpr float kClamp = 448.0f;       // e4m3fn max normal
constexpr int NB = 4;                  // point-batches per block in MLP kernel
constexpr int BLK = 256;
constexpr size_t kFeatBytes = (size_t)kNpts * 32;          // 32 MB fp8 feats
constexpr size_t kTb16Bytes = (size_t)16 * 524288 * 4;     // 32 MB bf16 tables

// MLP kernel LDS layout (bytes)
constexpr int W_OFF = 0;       // 36 frags * 512B = 18432 (fp8 A-fragments of W^T)
constexpr int B_OFF = 18432;   // 400 floats = 1600 (biases)
constexpr int S_OFF = 20032;   // 4 waves * 1152B (activation relayout scratch)
constexpr int LDS_BYTES = 24640;

struct ResArg { int r[16]; };

__device__ __forceinline__ unsigned char f2fp8(float v) {
  return (unsigned char)(__builtin_amdgcn_cvt_pk_fp8_f32(v, 0.f, 0, false) & 0xff);
}

template<int K, int OUT, int Kp, int OUTp, int FBASE>
__device__ __forceinline__ void prep_layer(char* wl, const float* __restrict__ w, int tid) {
  constexpr int N = Kp * OUTp;
  for (int e = tid; e < N; e += BLK) {
    const int k = e / OUTp, o = e % OUTp;
    const float v = (k < K && o < OUT) ? w[k * OUT + o] : 0.f;
    const int f = FBASE + (o >> 4) * (Kp >> 5) + (k >> 5);
    const int l = (o & 15) | (((k >> 3) & 3) << 4);
    wl[f * 512 + l * 8 + (k & 7)] = (char)f2fp8(v);
  }
}

__device__ __forceinline__ i64 ldsA(const char* wl, int f, int lane) {
  return *(const i64*)(wl + f * 512 + lane * 8);
}
__device__ __forceinline__ i64 rB(const char* scr, int p, int g, int h) {
  return *(const i64*)(scr + p * 72 + h * 32 + g * 8);
}
__device__ __forceinline__ float4v bias4(const float* bl, int boff, int t, int g) {
  return *(const float4v*)(bl + boff + t * 16 + g * 4) * kS;
}
__device__ __forceinline__ void store_act4(char* scr, const float4v a[4], int p, int g) {
  #pragma unroll
  for (int t = 0; t < 4; ++t) {
    const float x0 = fminf(fmaxf(a[t].x, 0.f), kClamp);
    const float x1 = fminf(fmaxf(a[t].y, 0.f), kClamp);
    const float x2 = fminf(fmaxf(a[t].z, 0.f), kClamp);
    const float x3 = fminf(fmaxf(a[t].w, 0.f), kClamp);
    int d = __builtin_amdgcn_cvt_pk_fp8_f32(x0, x1, 0, false);
    d = __builtin_amdgcn_cvt_pk_fp8_f32(x2, x3, d, true);
    *(int*)(scr + p * 72 + t * 16 + g * 4) = d;
  }
}

#define MFMA8(A, B, C) __builtin_amdgcn_mfma_f32_16x16x32_fp8_fp8((A), (B), (C), 0, 0, 0)
#define LDS_FENCE() __threadfence_block()

// ---- table conversion: fp32 float2 entries -> packed 2xbf16 (RN) uint -----
__global__ __launch_bounds__(BLK) void conv_tables(const float4* __restrict__ t4,
                                                   uint2* __restrict__ out) {
  const int i = blockIdx.x * BLK + threadIdx.x;   // handles 2 entries (16B in, 8B out)
  const float4 e = t4[i];
  unsigned x0 = __float_as_uint(e.x), y0 = __float_as_uint(e.y);
  unsigned x1 = __float_as_uint(e.z), y1 = __float_as_uint(e.w);
  x0 = (x0 + 0x7fffu + ((x0 >> 16) & 1u)) >> 16;
  y0 = (y0 + 0x7fffu + ((y0 >> 16) & 1u)) & 0xffff0000u;
  x1 = (x1 + 0x7fffu + ((x1 >> 16) & 1u)) >> 16;
  y1 = (y1 + 0x7fffu + ((y1 >> 16) & 1u)) & 0xffff0000u;
  out[i] = make_uint2(x0 | y0, x1 | y1);
}

// ---- Kernel A (bf16 tables): one thread = (point, level), x-pair merged ----
// bid = chunk*16 + level -> XCD = level%8: each XCD L2 sees levels {k,k+8}
// whose combined bf16 footprint is <= ~4MB (L2-resident).
__global__ __launch_bounds__(BLK, 8) void hash_gather_b16(
    const float* __restrict__ xyz, const unsigned* __restrict__ tb,
    unsigned char* __restrict__ feats, ResArg res) {
  const int bid = blockIdx.x;
  const int level = bid & 15;
  const int pt = (bid >> 4) * BLK + threadIdx.x;

  const float px = xyz[pt * 3 + 0];
  const float py = xyz[pt * 3 + 1];
  const float pz = xyz[pt * 3 + 2];

  const int R = res.r[level];
  const float Rf = (float)R;
  const unsigned* t = tb + (size_t)level * 524288u;
  const float sx = (px + 1.f) * 0.5f * (Rf - 1.f);
  const float sy = (py + 1.f) * 0.5f * (Rf - 1.f);
  const float sz = (pz + 1.f) * 0.5f * (Rf - 1.f);
  const float flx = floorf(sx), fly = floorf(sy), flz = floorf(sz);
  const float fxw = sx - flx, fyw = sy - fly, fzw = sz - flz;
  const int x0 = min(max((int)flx, 0), R - 1);
  const int y0 = min(max((int)fly, 0), R - 1);
  const int z0 = min(max((int)flz, 0), R - 1);
  const int x1 = min(x0 + 1, R - 1), y1 = min(y0 + 1, R - 1), z1 = min(z0 + 1, R - 1);
  const unsigned ux0 = (unsigned)x0, ux1 = (unsigned)x1;
  const unsigned hy0 = (unsigned)y0 * 2654435761u, hy1 = (unsigned)y1 * 2654435761u;
  const unsigned hz0 = (unsigned)z0 * 805459861u, hz1 = (unsigned)z1 * 805459861u;

  // 4 (y,z) combos; per combo idx(x1) differs from idx(x0) by bit0 iff x0 even
  unsigned A[4] = {hy0 ^ hz0, hy0 ^ hz1, hy1 ^ hz0, hy1 ^ hz1};
  unsigned i0[4], i1[4];
  uint2 pr[4];
#pragma unroll
  for (int k = 0; k < 4; ++k) {
    i0[k] = (A[k] ^ ux0) & kTmask;
    i1[k] = (A[k] ^ ux1) & kTmask;
    pr[k] = *(const uint2*)(t + (i0[k] & ~1u));   // 8B pair: entries idx&~1, idx|1
  }
  unsigned e0[4], e1[4];
#pragma unroll
  for (int k = 0; k < 4; ++k) {
    e0[k] = (i0[k] & 1u) ? pr[k].y : pr[k].x;
    unsigned sel = (i1[k] & 1u) ? pr[k].y : pr[k].x;  // valid when (i0^i1)<=1
    if ((i0[k] ^ i1[k]) > 1u) sel = t[i1[k]];         // exec-masked extra load
    e1[k] = sel;
  }
  const float wx1 = fxw, wx0 = 1.f - fxw;
  const float wy1 = fyw, wy0 = 1.f - fyw;
  const float wz1 = fzw, wz0 = 1.f - fzw;
  const float wyz[4] = {wy0 * wz0, wy0 * wz1, wy1 * wz0, wy1 * wz1};
  float a0 = 0.f, a1 = 0.f;
#pragma unroll
  for (int k = 0; k < 4; ++k) {
    const float f0x = __uint_as_float(e0[k] << 16);
    const float f0y = __uint_as_float(e0[k] & 0xffff0000u);
    const float f1x = __uint_as_float(e1[k] << 16);
    const float f1y = __uint_as_float(e1[k] & 0xffff0000u);
    a0 += wyz[k] * (wx0 * f0x + wx1 * f1x);
    a1 += wyz[k] * (wx0 * f0y + wx1 * f1y);
  }

  const unsigned v =
      (unsigned)__builtin_amdgcn_cvt_pk_fp8_f32(a0 * kS, a1 * kS, 0, false) & 0xffffu;
  *(unsigned short*)(feats + (size_t)(pt >> 4) * 512 + (level >> 2) * 128 +
                     (pt & 15) * 8 + ((2 * level) & 6)) = (unsigned short)v;
}

// ---- Kernel A fallback (f32 tables, used if ws too small) ------------------
__global__ __launch_bounds__(BLK, 8) void hash_gather_f32(
    const float* __restrict__ xyz, const float* __restrict__ tables,
    unsigned char* __restrict__ feats, ResArg res) {
  const int bid = blockIdx.x;
  const int level = bid & 15;
  const int pt = (bid >> 4) * BLK + threadIdx.x;
  const float px = xyz[pt * 3 + 0];
  const float py = xyz[pt * 3 + 1];
  const float pz = xyz[pt * 3 + 2];
  const int R = res.r[level];
  const float Rf = (float)R;
  const float2* t2 = reinterpret_cast<const float2*>(tables + (size_t)level * 1048576u);
  const float sx = (px + 1.f) * 0.5f * (Rf - 1.f);
  const float sy = (py + 1.f) * 0.5f * (Rf - 1.f);
  const float sz = (pz + 1.f) * 0.5f * (Rf - 1.f);
  const float flx = floorf(sx), fly = floorf(sy), flz = floorf(sz);
  const float fxw = sx - flx, fyw = sy - fly, fzw = sz - flz;
  const int x0 = min(max((int)flx, 0), R - 1);
  const int y0 = min(max((int)fly, 0), R - 1);
  const int z0 = min(max((int)flz, 0), R - 1);
  const int x1 = min(x0 + 1, R - 1), y1 = min(y0 + 1, R - 1), z1 = min(z0 + 1, R - 1);
  const unsigned hx0 = (unsigned)x0, hx1 = (unsigned)x1;
  const unsigned hy0 = (unsigned)y0 * 2654435761u, hy1 = (unsigned)y1 * 2654435761u;
  const unsigned hz0 = (unsigned)z0 * 805459861u, hz1 = (unsigned)z1 * 805459861u;
  const float2 e000 = t2[(hx0 ^ hy0 ^ hz0) & kTmask];
  const float2 e001 = t2[(hx0 ^ hy0 ^ hz1) & kTmask];
  const float2 e010 = t2[(hx0 ^ hy1 ^ hz0) & kTmask];
  const float2 e011 = t2[(hx0 ^ hy1 ^ hz1) & kTmask];
  const float2 e100 = t2[(hx1 ^ hy0 ^ hz0) & kTmask];
  const float2 e101 = t2[(hx1 ^ hy0 ^ hz1) & kTmask];
  const float2 e110 = t2[(hx1 ^ hy1 ^ hz0) & kTmask];
  const float2 e111 = t2[(hx1 ^ hy1 ^ hz1) & kTmask];
  const float wx1 = fxw, wx0 = 1.f - fxw;
  const float wy1 = fyw, wy0 = 1.f - fyw;
  const float wz1 = fzw, wz0 = 1.f - fzw;
  float a0 = 0.f, a1 = 0.f;
  float w;
  w = wx0 * wy0 * wz0; a0 = fmaf(w, e000.x, a0); a1 = fmaf(w, e000.y, a1);
  w = wx0 * wy0 * wz1; a0 = fmaf(w, e001.x, a0); a1 = fmaf(w, e001.y, a1);
  w = wx0 * wy1 * wz0; a0 = fmaf(w, e010.x, a0); a1 = fmaf(w, e010.y, a1);
  w = wx0 * wy1 * wz1; a0 = fmaf(w, e011.x, a0); a1 = fmaf(w, e011.y, a1);
  w = wx1 * wy0 * wz0; a0 = fmaf(w, e100.x, a0); a1 = fmaf(w, e100.y, a1);
  w = wx1 * wy0 * wz1; a0 = fmaf(w, e101.x, a0); a1 = fmaf(w, e101.y, a1);
  w = wx1 * wy1 * wz0; a0 = fmaf(w, e110.x, a0); a1 = fmaf(w, e110.y, a1);
  w = wx1 * wy1 * wz1; a0 = fmaf(w, e111.x, a0); a1 = fmaf(w, e111.y, a1);
  const unsigned v =
      (unsigned)__builtin_amdgcn_cvt_pk_fp8_f32(a0 * kS, a1 * kS, 0, false) & 0xffffu;
  *(unsigned short*)(feats + (size_t)(pt >> 4) * 512 + (level >> 2) * 128 +
                     (pt & 15) * 8 + ((2 * level) & 6)) = (unsigned short)v;
}

// ---------------- Kernel B: MFMA MLP over precomputed feats -----------------
__global__ __launch_bounds__(BLK, 4) void nerf_mlp(
    const unsigned char* __restrict__ feats,
    const float* __restrict__ w1, const float* __restrict__ b1,
    const float* __restrict__ w2, const float* __restrict__ b2,
    const float* __restrict__ w3, const float* __restrict__ b3,
    const float* __restrict__ cw1, const float* __restrict__ cb1,
    const float* __restrict__ cw2, const float* __restrict__ cb2,
    const float* __restrict__ cw3, const float* __restrict__ cb3,
    const float* __restrict__ cw4, const float* __restrict__ cb4,
    float* __restrict__ out_color, float* __restrict__ out_sigma) {
  __shared__ __align__(16) char smem[LDS_BYTES];
  const int tid = threadIdx.x;
  char* wl = smem + W_OFF;
  float* bl = (float*)(smem + B_OFF);

  prep_layer<32, 64, 32, 64, 0>(wl, w1, tid);
  prep_layer<64, 64, 64, 64, 4>(wl, w2, tid);
  prep_layer<64, 16, 64, 16, 12>(wl, w3, tid);
  prep_layer<16, 64, 32, 64, 14>(wl, cw1, tid);
  prep_layer<64, 64, 64, 64, 18>(wl, cw2, tid);
  prep_layer<64, 64, 64, 64, 26>(wl, cw3, tid);
  prep_layer<64, 3, 64, 16, 34>(wl, cw4, tid);
  if (tid < 64) {
    bl[0 + tid] = b1[tid];  bl[64 + tid] = b2[tid];
    bl[192 + tid] = cb1[tid]; bl[256 + tid] = cb2[tid]; bl[320 + tid] = cb3[tid];
  }
  if (tid < 16) { bl[128 + tid] = b3[tid]; bl[384 + tid] = (tid < 3) ? cb4[tid] : 0.f; }
  __syncthreads();

  const int lane = tid & 63, wave = tid >> 6;
  const int p = lane & 15, g = lane >> 4;
  char* scr = smem + S_OFF + wave * 1152;

  for (int b = 0; b < NB; ++b) {
    const int base = (blockIdx.x * NB + b) * BLK;
    const int ptb = base + wave * 64;
    for (int n = 0; n < 4; ++n) {
      const int tile = (ptb >> 4) + n;
      const i64 Bf = *(const i64*)(feats + (size_t)tile * 512 + g * 128 + p * 8);
      float4v a[4];
#pragma unroll
      for (int t = 0; t < 4; ++t) a[t] = MFMA8(ldsA(wl, 0 + t, lane), Bf, bias4(bl, 0, t, g));
      store_act4(scr, a, p, g);
      LDS_FENCE();
      i64 B0 = rB(scr, p, g, 0), B1 = rB(scr, p, g, 1);
#pragma unroll
      for (int t = 0; t < 4; ++t) {
        float4v c = bias4(bl, 64, t, g);
        c = MFMA8(ldsA(wl, 4 + 2 * t, lane), B0, c);
        a[t] = MFMA8(ldsA(wl, 5 + 2 * t, lane), B1, c);
      }
      store_act4(scr, a, p, g);
      LDS_FENCE();
      B0 = rB(scr, p, g, 0); B1 = rB(scr, p, g, 1);
      float4v f4 = bias4(bl, 128, 0, g);
      f4 = MFMA8(ldsA(wl, 12, lane), B0, f4);
      f4 = MFMA8(ldsA(wl, 13, lane), B1, f4);
      if (g == 0) out_sigma[ptb + n * 16 + p] = expf(f4.x * kInvS);
      {
        const float z0 = fminf(fmaxf(f4.x, -kClamp), kClamp);
        const float z1 = fminf(fmaxf(f4.y, -kClamp), kClamp);
        const float z2 = fminf(fmaxf(f4.z, -kClamp), kClamp);
        const float z3 = fminf(fmaxf(f4.w, -kClamp), kClamp);
        int d = __builtin_amdgcn_cvt_pk_fp8_f32(z0, z1, 0, false);
        d = __builtin_amdgcn_cvt_pk_fp8_f32(z2, z3, d, true);
        *(int*)(scr + p * 72 + g * 4) = d;
      }
      LDS_FENCE();
      const i64 Bc = rB(scr, p, g, 0);
#pragma unroll
      for (int t = 0; t < 4; ++t) a[t] = MFMA8(ldsA(wl, 14 + t, lane), Bc, bias4(bl, 192, t, g));
      store_act4(scr, a, p, g);
      LDS_FENCE();
      B0 = rB(scr, p, g, 0); B1 = rB(scr, p, g, 1);
#pragma unroll
      for (int t = 0; t < 4; ++t) {
        float4v c = bias4(bl, 256, t, g);
        c = MFMA8(ldsA(wl, 18 + 2 * t, lane), B0, c);
        a[t] = MFMA8(ldsA(wl, 19 + 2 * t, lane), B1, c);
      }
      store_act4(scr, a, p, g);
      LDS_FENCE();
      B0 = rB(scr, p, g, 0); B1 = rB(scr, p, g, 1);
#pragma unroll
      for (int t = 0; t < 4; ++t) {
        float4v c = bias4(bl, 320, t, g);
        c = MFMA8(ldsA(wl, 26 + 2 * t, lane), B0, c);
        a[t] = MFMA8(ldsA(wl, 27 + 2 * t, lane), B1, c);
      }
      store_act4(scr, a, p, g);
      LDS_FENCE();
      B0 = rB(scr, p, g, 0); B1 = rB(scr, p, g, 1);
      float4v c4 = bias4(bl, 384, 0, g);
      c4 = MFMA8(ldsA(wl, 34, lane), B0, c4);
      c4 = MFMA8(ldsA(wl, 35, lane), B1, c4);
      if (g == 0) {
        const int pt = ptb + n * 16 + p;
        out_color[pt * 3 + 0] = 1.f / (1.f + expf(-c4.x * kInvS));
        out_color[pt * 3 + 1] = 1.f / (1.f + expf(-c4.y * kInvS));
        out_color[pt * 3 + 2] = 1.f / (1.f + expf(-c4.z * kInvS));
      }
      LDS_FENCE();
    }
  }
}

}  // namespace

extern "C" void kernel_launch(void* const* d_in, const int* in_sizes, int n_in,
                              void* d_out, int out_size, void* d_ws, size_t ws_size,
                              hipStream_t stream) {
  const float* xyz = (const float*)d_in[0];
  const float* tables = (const float*)d_in[1];
  const float* w1 = (const float*)d_in[2];
  const float* b1 = (const float*)d_in[3];
  const float* w2 = (const float*)d_in[4];
  const float* b2 = (const float*)d_in[5];
  const float* w3 = (const float*)d_in[6];
  const float* b3 = (const float*)d_in[7];
  const float* cw1 = (const float*)d_in[8];
  const float* cb1 = (const float*)d_in[9];
  const float* cw2 = (const float*)d_in[10];
  const float* cb2 = (const float*)d_in[11];
  const float* cw3 = (const float*)d_in[12];
  const float* cb3 = (const float*)d_in[13];
  const float* cw4 = (const float*)d_in[14];
  const float* cb4 = (const float*)d_in[15];
  float* out = (float*)d_out;
  unsigned char* feats = (unsigned char*)d_ws;                    // 32 MB
  unsigned* tb16 = (unsigned*)((char*)d_ws + kFeatBytes);         // 32 MB

  ResArg ra;
  const double diff = log(2048.0) - log(16.0);
  for (int l = 0; l < 16; ++l) ra.r[l] = (int)floor(16.0 * exp((double)l * diff / 15.0));

  if (ws_size >= kFeatBytes + kTb16Bytes) {
    // 16 levels * 524288 entries / 2 entries per thread = 4194304 threads
    hipLaunchKernelGGL(conv_tables, dim3(4194304 / BLK), dim3(BLK), 0, stream,
                       (const float4*)tables, (uint2*)tb16);
    hipLaunchKernelGGL(hash_gather_b16, dim3((kNpts / BLK) * 16), dim3(BLK), 0, stream,
                       xyz, tb16, feats, ra);
  } else {
    hipLaunchKernelGGL(hash_gather_f32, dim3((kNpts / BLK) * 16), dim3(BLK), 0, stream,
                       xyz, tables, feats, ra);
  }
  hipLaunchKernelGGL(nerf_mlp, dim3(kNpts / (BLK * NB)), dim3(BLK), 0, stream,
                     feats, w1, b1, w2, b2, w3, b3, cw1, cb1, cw2, cb2, cw3, cb3,
                     cw4, cb4, out, out + (size_t)3 * kNpts);
}